// Round 7
// baseline (216.695 us; speedup 1.0000x reference)
//
#include <hip/hip_runtime.h>
#include <hip/hip_bf16.h>

#define N_EDGES_C 600000
#define D_C 128
#define NTILES 9375      // 600000 / 64, exact
#define GRIDB 1024

typedef __attribute__((ext_vector_type(8))) short short8;
typedef __attribute__((ext_vector_type(4))) float f32x4;

__device__ inline unsigned short f2bf(float f) {
    unsigned int u = __builtin_bit_cast(unsigned int, f);
    u += 0x7FFF + ((u >> 16) & 1);          // round-nearest-even
    return (unsigned short)(u >> 16);
}

__device__ inline unsigned int pk2bf(float lo, float hi) {
    return (unsigned int)f2bf(lo) | ((unsigned int)f2bf(hi) << 16);
}

// Fragment-ordered W1 (bf16): w1f[((nf*8+kk)*64 + lane)*8 + j] =
//   W1[(kk*32 + (lane>>4)*8 + j) * 256 + nf*16 + (lane&15)]
__global__ void prep_w1f(const float* __restrict__ W1, unsigned short* __restrict__ w1f) {
    int o = blockIdx.x * 256 + threadIdx.x;   // 0..65535
    int j    = o & 7;
    int lane = (o >> 3) & 63;
    int kk   = (o >> 9) & 7;
    int nf   = o >> 12;
    int k = kk * 32 + (lane >> 4) * 8 + j;
    int n = nf * 16 + (lane & 15);
    w1f[o] = f2bf(W1[k * 256 + n]);
}

// Persistent double-buffered pipeline:
//   per tile: {issue gathers(t+1) -> regs | barrier | MFMA(t) | epilogue |
//              ds_write regs -> other buf | barrier | out-write(t)}
// A-tile fragment order with lane-window-safe swizzle:
//   logical (row = m*16+rr, k = kk*32+kl*8+j) at
//   smem[buf][(m*8+kk)*1024 + (kl*16 + (rr ^ ((kk^(kl<<1))&7)))*16 + j*2]
// Write: lanes 0..15 cover all 16 bank-pairs exactly once (enumerated).
// Read: bijective per (kk,kl) -> full 1KB contiguous-class read, conflict-free.
__global__ __launch_bounds__(256, 2) void edge_mlp(
    const float* __restrict__ emd,
    const int* __restrict__ eidx,
    const unsigned short* __restrict__ w1f,
    const float* __restrict__ b1,
    const float* __restrict__ W2,
    const float* __restrict__ b2,
    float* __restrict__ out)
{
    extern __shared__ unsigned char smem[];        // 2 x 32768 A-bufs + 1KB partial
    float* partial = (float*)(smem + 65536);       // [4 waves][64 rows]

    const int t    = threadIdx.x;
    const int lane = t & 63;
    const int wv   = t >> 6;
    const int rr_c = lane & 15;
    const int lg   = lane >> 4;

    // staging lane constants
    const int L    = lane & 31;                    // float4 index in embed row
    const int kkw  = (lane >> 5) * 4 + (L >> 3);   // k-block this lane's 4 floats fall in
    const int klw  = (L >> 1) & 3;
    const int wbase = kkw * 1024 + klw * 256 + (lane & 1) * 8;
    const int wxor  = (kkw ^ (klw << 1)) & 7;

    // a-read lane constant: kl = lane>>4 -> xor term (kk ^ (kl<<1))&7
    const int klsh = (lane >> 4) << 1;

    // hoisted per-block epilogue constants
    float b1v[4], w2v[4];
    #pragma unroll
    for (int n4 = 0; n4 < 4; ++n4) {
        int n = wv * 64 + n4 * 16 + rr_c;
        b1v[n4] = b1[n];
        w2v[n4] = W2[n];
    }
    const float b2v = b2[0];

    int tile = blockIdx.x;                         // GRIDB < NTILES always

    // ---- prologue: stage first tile into buf 0 ----
    {
        uint2 pk[16];
        #pragma unroll
        for (int p = 0; p < 16; ++p) {
            const int row = p * 4 + wv;
            const int2 ep = *reinterpret_cast<const int2*>(eidx + (size_t)(tile * 64 + row) * 2);
            const int idx = (lane < 32) ? ep.x : ep.y;
            const float4 v = *reinterpret_cast<const float4*>(emd + (size_t)idx * D_C + L * 4);
            pk[p].x = pk2bf(v.x, v.y);
            pk[p].y = pk2bf(v.z, v.w);
        }
        #pragma unroll
        for (int p = 0; p < 16; ++p) {
            const int row = p * 4 + wv;
            *reinterpret_cast<uint2*>(smem +
                ((row >> 4) * 8192 + wbase + (((row & 15) ^ wxor) << 4))) = pk[p];
        }
    }

    int cur = 0;
    for (; tile < NTILES; tile += GRIDB) {
        const int ntile = tile + GRIDB;
        const bool has_next = ntile < NTILES;

        // 1. issue gathers for next tile -> regs (latency hides under MFMA below)
        uint2 pk[16];
        if (has_next) {
            #pragma unroll
            for (int p = 0; p < 16; ++p) {
                const int row = p * 4 + wv;
                const int2 ep = *reinterpret_cast<const int2*>(eidx + (size_t)(ntile * 64 + row) * 2);
                const int idx = (lane < 32) ? ep.x : ep.y;
                const float4 v = *reinterpret_cast<const float4*>(emd + (size_t)idx * D_C + L * 4);
                pk[p].x = pk2bf(v.x, v.y);
                pk[p].y = pk2bf(v.z, v.w);
            }
        }

        // 2. buf[cur] writes (prev iter / prologue) visible
        __syncthreads();

        // 3. MFMA from buf[cur]
        const unsigned char* buf = smem + cur * 32768;
        f32x4 acc[4][4];
        #pragma unroll
        for (int m = 0; m < 4; ++m)
            #pragma unroll
            for (int n4 = 0; n4 < 4; ++n4) acc[m][n4] = (f32x4){0.f, 0.f, 0.f, 0.f};

        #pragma unroll
        for (int kk = 0; kk < 8; ++kk) {
            const int aoff = ((lane & 48) | (rr_c ^ ((kk ^ klsh) & 7))) << 4;
            short8 a[4];
            #pragma unroll
            for (int m = 0; m < 4; ++m)
                a[m] = *reinterpret_cast<const short8*>(buf + (m * 8 + kk) * 1024 + aoff);
            #pragma unroll
            for (int n4 = 0; n4 < 4; ++n4) {
                short8 b = *reinterpret_cast<const short8*>(
                    w1f + ((size_t)((wv * 4 + n4) * 8 + kk) * 64 + lane) * 8);
                #pragma unroll
                for (int m = 0; m < 4; ++m)
                    acc[m][n4] = __builtin_amdgcn_mfma_f32_16x16x32_bf16(a[m], b, acc[m][n4], 0, 0, 0);
            }
        }

        // 4. fused epilogue: relu(acc+b1)*W2 -> per-lane partials -> shfl reduce
        float pr[4][4];
        #pragma unroll
        for (int m = 0; m < 4; ++m)
            #pragma unroll
            for (int g = 0; g < 4; ++g) pr[m][g] = 0.f;

        #pragma unroll
        for (int n4 = 0; n4 < 4; ++n4) {
            #pragma unroll
            for (int m = 0; m < 4; ++m)
                #pragma unroll
                for (int g = 0; g < 4; ++g) {
                    float h = acc[m][n4][g] + b1v[n4];
                    h = h > 0.f ? h : 0.f;
                    pr[m][g] += h * w2v[n4];
                }
        }
        #pragma unroll
        for (int msk = 8; msk >= 1; msk >>= 1) {
            #pragma unroll
            for (int m = 0; m < 4; ++m)
                #pragma unroll
                for (int g = 0; g < 4; ++g)
                    pr[m][g] += __shfl_xor(pr[m][g], msk, 64);
        }
        if (rr_c == 0) {
            #pragma unroll
            for (int m = 0; m < 4; ++m)
                #pragma unroll
                for (int g = 0; g < 4; ++g)
                    partial[wv * 64 + m * 16 + lg * 4 + g] = pr[m][g];
        }

        // 5. drain staged regs into the other buffer
        if (has_next) {
            unsigned char* nbuf = smem + (cur ^ 1) * 32768;
            #pragma unroll
            for (int p = 0; p < 16; ++p) {
                const int row = p * 4 + wv;
                *reinterpret_cast<uint2*>(nbuf +
                    ((row >> 4) * 8192 + wbase + (((row & 15) ^ wxor) << 4))) = pk[p];
            }
        }

        // 6. partials + next-buf writes visible
        __syncthreads();

        // 7. final cross-wave sum + sigmoid
        if (t < 64) {
            float s = partial[t] + partial[64 + t] + partial[128 + t] + partial[192 + t] + b2v;
            out[(size_t)tile * 64 + t] = 1.0f / (1.0f + __expf(-s));
        }
        cur ^= 1;
    }
}

extern "C" void kernel_launch(void* const* d_in, const int* in_sizes, int n_in,
                              void* d_out, int out_size, void* d_ws, size_t ws_size,
                              hipStream_t stream) {
    const float* emd  = (const float*)d_in[0];
    const int*   eidx = (const int*)d_in[1];
    const float* W1   = (const float*)d_in[2];
    const float* b1   = (const float*)d_in[3];
    const float* W2   = (const float*)d_in[4];
    const float* b2   = (const float*)d_in[5];
    float* out = (float*)d_out;
    unsigned short* w1f = (unsigned short*)d_ws;   // 256*256 bf16 = 128KB, fragment-ordered

    prep_w1f<<<256, 256, 0, stream>>>(W1, w1f);

    const size_t lds_bytes = 2 * 32768 + 256 * sizeof(float);   // 66560
    edge_mlp<<<GRIDB, 256, lds_bytes, stream>>>(emd, eidx, w1f, b1, W2, b2, out);
}

// Round 8
// 186.610 us; speedup vs baseline: 1.1612x; 1.1612x over previous
//
#include <hip/hip_runtime.h>
#include <hip/hip_bf16.h>

#define N_EDGES_C 600000
#define D_C 128
#define NTILES 9375      // 600000 / 64, exact
#define GRIDB 1875       // NTILES / GRIDB = 5 tiles per block, exact
#define TPB 5

typedef __attribute__((ext_vector_type(8))) short short8;
typedef __attribute__((ext_vector_type(4))) float f32x4;

__device__ inline unsigned short f2bf(float f) {
    unsigned int u = __builtin_bit_cast(unsigned int, f);
    u += 0x7FFF + ((u >> 16) & 1);          // round-nearest-even
    return (unsigned short)(u >> 16);
}

__device__ inline unsigned int pk2bf(float lo, float hi) {
    return (unsigned int)f2bf(lo) | ((unsigned int)f2bf(hi) << 16);
}

// Fragment-ordered W1 (bf16): w1f[((nf*8+kk)*64 + lane)*8 + j] =
//   W1[(kk*32 + (lane>>4)*8 + j) * 256 + nf*16 + (lane&15)]
__global__ void prep_w1f(const float* __restrict__ W1, unsigned short* __restrict__ w1f) {
    int o = blockIdx.x * 256 + threadIdx.x;   // 0..65535
    int j    = o & 7;
    int lane = (o >> 3) & 63;
    int kk   = (o >> 9) & 7;
    int nf   = o >> 12;
    int k = kk * 32 + (lane >> 4) * 8 + j;
    int n = nf * 16 + (lane & 15);
    w1f[o] = f2bf(W1[k * 256 + n]);
}

// Persistent double-buffered pipeline (spill-fixed):
//   per tile: {issue gathers(t+1)->regs | barrier | MFMA(t) | drain regs->other
//              buf | epilogue | barrier | out-write(t)}
// A-tile fragment order, both-sides swizzle (R7: measured 0 bank conflicts):
//   logical (row = m*16+rr, k = kk*32+kl*8+j) at
//   smem[buf][(m*8+kk)*1024 + (kl*16 + (rr ^ ((kk^(kl<<1))&7)))*16 + j*2]
__global__ __launch_bounds__(256, 1) void edge_mlp(
    const float* __restrict__ emd,
    const int* __restrict__ eidx,
    const unsigned short* __restrict__ w1f,
    const float* __restrict__ b1,
    const float* __restrict__ W2,
    const float* __restrict__ b2,
    float* __restrict__ out)
{
    extern __shared__ unsigned char smem[];        // 2 x 32768 A-bufs + 1KB partial
    float* partial = (float*)(smem + 65536);       // [4 waves][64 rows]

    const int t    = threadIdx.x;
    const int lane = t & 63;
    const int wv   = t >> 6;
    const int rr_c = lane & 15;
    const int lg   = lane >> 4;

    // staging lane constants
    const int L    = lane & 31;                    // float4 index in embed row
    const int kkw  = (lane >> 5) * 4 + (L >> 3);   // k-block of this lane's 4 floats
    const int klw  = (L >> 1) & 3;
    const int wbase = kkw * 1024 + klw * 256 + (lane & 1) * 8;
    const int wxor  = (kkw ^ (klw << 1)) & 7;

    // a-read lane constant
    const int klsh = (lane >> 4) << 1;

    // hoisted epilogue constants
    float b1v[4], w2v[4];
    #pragma unroll
    for (int n4 = 0; n4 < 4; ++n4) {
        int n = wv * 64 + n4 * 16 + rr_c;
        b1v[n4] = b1[n];
        w2v[n4] = W2[n];
    }
    const float b2v = b2[0];

    int tile = blockIdx.x;

    // ---- prologue: stage first tile into buf 0 ----
    {
        uint2 pk[16];
        #pragma unroll
        for (int p = 0; p < 16; ++p) {
            const int row = p * 4 + wv;
            const int2 ep = *reinterpret_cast<const int2*>(eidx + (size_t)(tile * 64 + row) * 2);
            const int idx = (lane < 32) ? ep.x : ep.y;
            const float4 v = *reinterpret_cast<const float4*>(emd + (size_t)idx * D_C + L * 4);
            pk[p].x = pk2bf(v.x, v.y);
            pk[p].y = pk2bf(v.z, v.w);
        }
        #pragma unroll
        for (int p = 0; p < 16; ++p) {
            const int row = p * 4 + wv;
            *reinterpret_cast<uint2*>(smem +
                ((row >> 4) * 8192 + wbase + (((row & 15) ^ wxor) << 4))) = pk[p];
        }
    }

    int cur = 0;
    #pragma unroll 1
    for (int it = 0; it < TPB; ++it, tile += GRIDB) {
        const bool has_next = (it + 1) < TPB;
        const int ntile = tile + GRIDB;

        // 1. issue gathers for next tile -> regs (latency hides under MFMA)
        uint2 pk[16];
        if (has_next) {
            #pragma unroll
            for (int p = 0; p < 16; ++p) {
                const int row = p * 4 + wv;
                const int2 ep = *reinterpret_cast<const int2*>(eidx + (size_t)(ntile * 64 + row) * 2);
                const int idx = (lane < 32) ? ep.x : ep.y;
                const float4 v = *reinterpret_cast<const float4*>(emd + (size_t)idx * D_C + L * 4);
                pk[p].x = pk2bf(v.x, v.y);
                pk[p].y = pk2bf(v.z, v.w);
            }
        }

        // 2. buf[cur] writes (prev iter / prologue) visible
        __syncthreads();

        // 3. MFMA from buf[cur]
        const unsigned char* buf = smem + cur * 32768;
        f32x4 acc[4][4];
        #pragma unroll
        for (int m = 0; m < 4; ++m)
            #pragma unroll
            for (int n4 = 0; n4 < 4; ++n4) acc[m][n4] = (f32x4){0.f, 0.f, 0.f, 0.f};

        #pragma unroll
        for (int kk = 0; kk < 8; ++kk) {
            const int aoff = ((lane & 48) | (rr_c ^ ((kk ^ klsh) & 7))) << 4;
            short8 a[4];
            #pragma unroll
            for (int m = 0; m < 4; ++m)
                a[m] = *reinterpret_cast<const short8*>(buf + (m * 8 + kk) * 1024 + aoff);
            #pragma unroll
            for (int n4 = 0; n4 < 4; ++n4) {
                short8 b = *reinterpret_cast<const short8*>(
                    w1f + ((size_t)((wv * 4 + n4) * 8 + kk) * 64 + lane) * 8);
                #pragma unroll
                for (int m = 0; m < 4; ++m)
                    acc[m][n4] = __builtin_amdgcn_mfma_f32_16x16x32_bf16(a[m], b, acc[m][n4], 0, 0, 0);
            }
        }

        // 4. drain staged regs early (ends pk live range before epilogue)
        if (has_next) {
            unsigned char* nbuf = smem + (cur ^ 1) * 32768;
            #pragma unroll
            for (int p = 0; p < 16; ++p) {
                const int row = p * 4 + wv;
                *reinterpret_cast<uint2*>(nbuf +
                    ((row >> 4) * 8192 + wbase + (((row & 15) ^ wxor) << 4))) = pk[p];
            }
        }

        // 5. fused epilogue: relu(acc+b1)*W2 -> per-lane partials -> shfl reduce
        float pr[4][4];
        #pragma unroll
        for (int m = 0; m < 4; ++m)
            #pragma unroll
            for (int g = 0; g < 4; ++g) pr[m][g] = 0.f;

        #pragma unroll
        for (int n4 = 0; n4 < 4; ++n4) {
            #pragma unroll
            for (int m = 0; m < 4; ++m)
                #pragma unroll
                for (int g = 0; g < 4; ++g) {
                    float h = acc[m][n4][g] + b1v[n4];
                    h = h > 0.f ? h : 0.f;
                    pr[m][g] += h * w2v[n4];
                }
        }
        #pragma unroll
        for (int msk = 8; msk >= 1; msk >>= 1) {
            #pragma unroll
            for (int m = 0; m < 4; ++m)
                #pragma unroll
                for (int g = 0; g < 4; ++g)
                    pr[m][g] += __shfl_xor(pr[m][g], msk, 64);
        }
        if (rr_c == 0) {
            #pragma unroll
            for (int m = 0; m < 4; ++m)
                #pragma unroll
                for (int g = 0; g < 4; ++g)
                    partial[wv * 64 + m * 16 + lg * 4 + g] = pr[m][g];
        }

        // 6. partials + next-buf writes visible
        __syncthreads();

        // 7. final cross-wave sum + sigmoid
        if (t < 64) {
            float s = partial[t] + partial[64 + t] + partial[128 + t] + partial[192 + t] + b2v;
            out[(size_t)tile * 64 + t] = 1.0f / (1.0f + __expf(-s));
        }
        cur ^= 1;
    }
}

extern "C" void kernel_launch(void* const* d_in, const int* in_sizes, int n_in,
                              void* d_out, int out_size, void* d_ws, size_t ws_size,
                              hipStream_t stream) {
    const float* emd  = (const float*)d_in[0];
    const int*   eidx = (const int*)d_in[1];
    const float* W1   = (const float*)d_in[2];
    const float* b1   = (const float*)d_in[3];
    const float* W2   = (const float*)d_in[4];
    const float* b2   = (const float*)d_in[5];
    float* out = (float*)d_out;
    unsigned short* w1f = (unsigned short*)d_ws;   // 256*256 bf16 = 128KB, fragment-ordered

    prep_w1f<<<256, 256, 0, stream>>>(W1, w1f);

    const size_t lds_bytes = 2 * 32768 + 256 * sizeof(float);   // 66560
    edge_mlp<<<GRIDB, 256, lds_bytes, stream>>>(emd, eidx, w1f, b1, W2, b2, out);
}

// Round 9
// 162.021 us; speedup vs baseline: 1.3375x; 1.1518x over previous
//
#include <hip/hip_runtime.h>
#include <hip/hip_bf16.h>

#define N_EDGES_C 600000
#define D_C 128

typedef __attribute__((ext_vector_type(8))) short short8;
typedef __attribute__((ext_vector_type(4))) float f32x4;

__device__ inline unsigned short f2bf(float f) {
    unsigned int u = __builtin_bit_cast(unsigned int, f);
    u += 0x7FFF + ((u >> 16) & 1);          // round-nearest-even
    return (unsigned short)(u >> 16);
}

__device__ inline unsigned int pk2bf(float lo, float hi) {
    return (unsigned int)f2bf(lo) | ((unsigned int)f2bf(hi) << 16);
}

// Fragment-ordered W1 (bf16): w1f[((nf*8+kk)*64 + lane)*8 + j] =
//   W1[(kk*32 + (lane>>4)*8 + j) * 256 + nf*16 + (lane&15)]
__global__ void prep_w1f(const float* __restrict__ W1, unsigned short* __restrict__ w1f) {
    int o = blockIdx.x * 256 + threadIdx.x;   // 0..65535
    int j    = o & 7;
    int lane = (o >> 3) & 63;
    int kk   = (o >> 9) & 7;
    int nf   = o >> 12;
    int k = kk * 32 + (lane >> 4) * 8 + j;
    int n = nf * 16 + (lane & 15);
    w1f[o] = f2bf(W1[k * 256 + n]);
}

// Single tile per block; A-tile in MFMA fragment order with the R7-proven
// conflict-free both-sides swizzle:
//   logical (row = m*16+rr, k = kk*32+kl*8+j) at
//   smem[(m*8+kk)*1024 + (kl*16 + (rr ^ ((kk^(kl<<1))&7)))*16 + j*2]
// Staging: one edge row per wave-instr (2x512B coalesced global reads);
// LDS write covers all 16 bank-pairs once per 16-lane window (0 conflicts, R7).
__global__ __launch_bounds__(256, 4) void edge_mlp(
    const float* __restrict__ emd,
    const int* __restrict__ eidx,
    const unsigned short* __restrict__ w1f,
    const float* __restrict__ b1,
    const float* __restrict__ W2,
    const float* __restrict__ b2,
    float* __restrict__ out)
{
    __shared__ unsigned char smem[32768];

    const int t    = threadIdx.x;
    const int lane = t & 63;
    const int wv   = t >> 6;
    const int rr_c = lane & 15;
    const int lg   = lane >> 4;

    const int e0 = blockIdx.x * 64;

    // ---- stage: per p, wave wv stages edge row p*4+wv (coalesced) ----
    {
        const int L    = lane & 31;                    // float4 index in embed row
        const int kkw  = (lane >> 5) * 4 + (L >> 3);   // k-block of this lane's 4 floats
        const int klw  = (L >> 1) & 3;
        const int wbase = kkw * 1024 + klw * 256 + (lane & 1) * 8;
        const int wxor  = (kkw ^ (klw << 1)) & 7;

        #pragma unroll
        for (int p = 0; p < 16; ++p) {
            const int row = p * 4 + wv;
            const int2 ep = *reinterpret_cast<const int2*>(eidx + (size_t)(e0 + row) * 2);
            const int idx = (lane < 32) ? ep.x : ep.y;
            const float4 v = *reinterpret_cast<const float4*>(emd + (size_t)idx * D_C + L * 4);
            uint2 pk;
            pk.x = pk2bf(v.x, v.y);
            pk.y = pk2bf(v.z, v.w);
            *reinterpret_cast<uint2*>(smem +
                ((row >> 4) * 8192 + wbase + (((row & 15) ^ wxor) << 4))) = pk;
        }
    }
    __syncthreads();

    // ---- MFMA: each wave computes all 64 rows x its 64 output cols ----
    const int klsh = (lane >> 4) << 1;
    f32x4 acc[4][4];              // [m-frag][n-frag]
    #pragma unroll
    for (int m = 0; m < 4; ++m)
        #pragma unroll
        for (int n4 = 0; n4 < 4; ++n4) acc[m][n4] = (f32x4){0.f, 0.f, 0.f, 0.f};

    #pragma unroll
    for (int kk = 0; kk < 8; ++kk) {
        const int aoff = ((lane & 48) | (rr_c ^ ((kk ^ klsh) & 7))) << 4;
        short8 a[4];
        #pragma unroll
        for (int m = 0; m < 4; ++m)
            a[m] = *reinterpret_cast<const short8*>(smem + (m * 8 + kk) * 1024 + aoff);
        #pragma unroll
        for (int n4 = 0; n4 < 4; ++n4) {
            short8 b = *reinterpret_cast<const short8*>(
                w1f + ((size_t)((wv * 4 + n4) * 8 + kk) * 64 + lane) * 8);
            #pragma unroll
            for (int m = 0; m < 4; ++m)
                acc[m][n4] = __builtin_amdgcn_mfma_f32_16x16x32_bf16(a[m], b, acc[m][n4], 0, 0, 0);
        }
    }

    // ---- fused epilogue: relu(acc + b1) * W2 -> per-lane partial logits ----
    float pr[4][4];
    #pragma unroll
    for (int m = 0; m < 4; ++m)
        #pragma unroll
        for (int g = 0; g < 4; ++g) pr[m][g] = 0.f;

    #pragma unroll
    for (int n4 = 0; n4 < 4; ++n4) {
        int n = wv * 64 + n4 * 16 + rr_c;    // C/D col = lane&15
        float b1v = b1[n];
        float w2v = W2[n];
        #pragma unroll
        for (int m = 0; m < 4; ++m)
            #pragma unroll
            for (int g = 0; g < 4; ++g) {
                float h = acc[m][n4][g] + b1v;
                h = h > 0.f ? h : 0.f;
                pr[m][g] += h * w2v;
            }
    }

    // reduce over the 16 cols held across rr_c lanes
    #pragma unroll
    for (int msk = 8; msk >= 1; msk >>= 1) {
        #pragma unroll
        for (int m = 0; m < 4; ++m)
            #pragma unroll
            for (int g = 0; g < 4; ++g)
                pr[m][g] += __shfl_xor(pr[m][g], msk, 64);
    }

    __syncthreads();                 // A-tile reads done; safe to reuse smem
    float* partial = (float*)smem;   // [4 waves][64 rows]

    if (rr_c == 0) {
        #pragma unroll
        for (int m = 0; m < 4; ++m)
            #pragma unroll
            for (int g = 0; g < 4; ++g)
                partial[wv * 64 + m * 16 + lg * 4 + g] = pr[m][g];
    }
    __syncthreads();

    // final cross-wave sum + sigmoid
    if (t < 64) {
        float s = partial[t] + partial[64 + t] + partial[128 + t] + partial[192 + t] + b2[0];
        out[e0 + t] = 1.0f / (1.0f + __expf(-s));
    }
}

extern "C" void kernel_launch(void* const* d_in, const int* in_sizes, int n_in,
                              void* d_out, int out_size, void* d_ws, size_t ws_size,
                              hipStream_t stream) {
    const float* emd  = (const float*)d_in[0];
    const int*   eidx = (const int*)d_in[1];
    const float* W1   = (const float*)d_in[2];
    const float* b1   = (const float*)d_in[3];
    const float* W2   = (const float*)d_in[4];
    const float* b2   = (const float*)d_in[5];
    float* out = (float*)d_out;
    unsigned short* w1f = (unsigned short*)d_ws;   // 256*256 bf16 = 128KB, fragment-ordered

    prep_w1f<<<256, 256, 0, stream>>>(W1, w1f);

    const int nblocks = N_EDGES_C / 64;            // 9375, exact
    edge_mlp<<<nblocks, 256, 0, stream>>>(emd, eidx, w1f, b1, W2, b2, out);
}

// Round 10
// 141.305 us; speedup vs baseline: 1.5335x; 1.1466x over previous
//
#include <hip/hip_runtime.h>
#include <hip/hip_bf16.h>

#define N_EDGES_C 600000
#define D_C 128

typedef __attribute__((ext_vector_type(8))) short short8;
typedef __attribute__((ext_vector_type(4))) float f32x4;

__device__ inline unsigned short f2bf(float f) {
    unsigned int u = __builtin_bit_cast(unsigned int, f);
    u += 0x7FFF + ((u >> 16) & 1);          // round-nearest-even
    return (unsigned short)(u >> 16);
}

__device__ inline unsigned int pk2bf(float lo, float hi) {
    return (unsigned int)f2bf(lo) | ((unsigned int)f2bf(hi) << 16);
}

// Fragment-ordered W1 (bf16): w1f[((nf*8+kk)*64 + lane)*8 + j] =
//   W1[(kk*32 + (lane>>4)*8 + j) * 256 + nf*16 + (lane&15)]
__global__ void prep_w1f(const float* __restrict__ W1, unsigned short* __restrict__ w1f) {
    int o = blockIdx.x * 256 + threadIdx.x;   // 0..65535
    int j    = o & 7;
    int lane = (o >> 3) & 63;
    int kk   = (o >> 9) & 7;
    int nf   = o >> 12;
    int k = kk * 32 + (lane >> 4) * 8 + j;
    int n = nf * 16 + (lane & 15);
    w1f[o] = f2bf(W1[k * 256 + n]);
}

// 512-thread blocks (8 waves), 64-edge tile, N-split 8 waves x 32 cols.
// A-tile in MFMA fragment order, R7-proven conflict-free both-sides swizzle:
//   logical (row = m*16+rr, k = kk*32+kl*8+j) at
//   smem[(m*8+kk)*1024 + (kl*16 + (rr ^ ((kk^(kl<<1))&7)))*16 + j*2]
// VGPR budget: acc 32 + 1 live a-frag + 2 b-frags + addr ~= 56 (target <=64
// so 8 waves/SIMD -> up to 32 waves/CU with 32KB LDS -> 4-5 blocks/CU).
__global__ __launch_bounds__(512, 8) void edge_mlp(
    const float* __restrict__ emd,
    const int* __restrict__ eidx,
    const unsigned short* __restrict__ w1f,
    const float* __restrict__ b1,
    const float* __restrict__ W2,
    const float* __restrict__ b2,
    float* __restrict__ out)
{
    __shared__ unsigned char smem[32768];

    const int t    = threadIdx.x;
    const int lane = t & 63;
    const int wv   = t >> 6;      // 0..7; wave computes n-cols wv*32..+31
    const int rr_c = lane & 15;
    const int lg   = lane >> 4;

    const int e0 = blockIdx.x * 64;

    // ---- stage: per p, wave wv stages edge row p*8+wv (coalesced) ----
    {
        const int L    = lane & 31;                    // float4 index in embed row
        const int kkw  = (lane >> 5) * 4 + (L >> 3);   // k-block of this lane's 4 floats
        const int klw  = (L >> 1) & 3;
        const int wbase = kkw * 1024 + klw * 256 + (lane & 1) * 8;
        const int wxor  = (kkw ^ (klw << 1)) & 7;

        #pragma unroll
        for (int p = 0; p < 8; ++p) {
            const int row = p * 8 + wv;
            const int2 ep = *reinterpret_cast<const int2*>(eidx + (size_t)(e0 + row) * 2);
            const int idx = (lane < 32) ? ep.x : ep.y;
            const float4 v = *reinterpret_cast<const float4*>(emd + (size_t)idx * D_C + L * 4);
            uint2 pk;
            pk.x = pk2bf(v.x, v.y);
            pk.y = pk2bf(v.z, v.w);
            *reinterpret_cast<uint2*>(smem +
                ((row >> 4) * 8192 + wbase + (((row & 15) ^ wxor) << 4))) = pk;
        }
    }
    __syncthreads();

    // ---- MFMA: each wave computes all 64 rows x its 32 output cols ----
    const int klsh = (lane >> 4) << 1;
    f32x4 acc[4][2];              // [m-frag][n-frag]
    #pragma unroll
    for (int m = 0; m < 4; ++m)
        #pragma unroll
        for (int n4 = 0; n4 < 2; ++n4) acc[m][n4] = (f32x4){0.f, 0.f, 0.f, 0.f};

    #pragma unroll
    for (int kk = 0; kk < 8; ++kk) {
        const int aoff = ((lane & 48) | (rr_c ^ ((kk ^ klsh) & 7))) << 4;
        short8 b0 = *reinterpret_cast<const short8*>(
            w1f + ((size_t)((wv * 2 + 0) * 8 + kk) * 64 + lane) * 8);
        short8 b1f = *reinterpret_cast<const short8*>(
            w1f + ((size_t)((wv * 2 + 1) * 8 + kk) * 64 + lane) * 8);
        #pragma unroll
        for (int m = 0; m < 4; ++m) {
            short8 a = *reinterpret_cast<const short8*>(smem + (m * 8 + kk) * 1024 + aoff);
            acc[m][0] = __builtin_amdgcn_mfma_f32_16x16x32_bf16(a, b0,  acc[m][0], 0, 0, 0);
            acc[m][1] = __builtin_amdgcn_mfma_f32_16x16x32_bf16(a, b1f, acc[m][1], 0, 0, 0);
        }
    }

    // ---- fused epilogue: relu(acc + b1) * W2 -> per-lane partial logits ----
    float pr[4][4];
    #pragma unroll
    for (int m = 0; m < 4; ++m)
        #pragma unroll
        for (int g = 0; g < 4; ++g) pr[m][g] = 0.f;

    #pragma unroll
    for (int n4 = 0; n4 < 2; ++n4) {
        int n = wv * 32 + n4 * 16 + rr_c;    // C/D col = lane&15
        float b1v = b1[n];
        float w2v = W2[n];
        #pragma unroll
        for (int m = 0; m < 4; ++m)
            #pragma unroll
            for (int g = 0; g < 4; ++g) {
                float h = acc[m][n4][g] + b1v;
                h = h > 0.f ? h : 0.f;
                pr[m][g] += h * w2v;
            }
    }

    // reduce over the 16 cols held across rr_c lanes
    #pragma unroll
    for (int msk = 8; msk >= 1; msk >>= 1) {
        #pragma unroll
        for (int m = 0; m < 4; ++m)
            #pragma unroll
            for (int g = 0; g < 4; ++g)
                pr[m][g] += __shfl_xor(pr[m][g], msk, 64);
    }

    __syncthreads();                 // A-tile reads done; safe to reuse smem
    float* partial = (float*)smem;   // [8 waves][64 rows]

    if (rr_c == 0) {
        #pragma unroll
        for (int m = 0; m < 4; ++m)
            #pragma unroll
            for (int g = 0; g < 4; ++g)
                partial[wv * 64 + m * 16 + lg * 4 + g] = pr[m][g];
    }
    __syncthreads();

    // final cross-wave sum + sigmoid
    if (t < 64) {
        float s = b2[0];
        #pragma unroll
        for (int w = 0; w < 8; ++w) s += partial[w * 64 + t];
        out[e0 + t] = 1.0f / (1.0f + __expf(-s));
    }
}

extern "C" void kernel_launch(void* const* d_in, const int* in_sizes, int n_in,
                              void* d_out, int out_size, void* d_ws, size_t ws_size,
                              hipStream_t stream) {
    const float* emd  = (const float*)d_in[0];
    const int*   eidx = (const int*)d_in[1];
    const float* W1   = (const float*)d_in[2];
    const float* b1   = (const float*)d_in[3];
    const float* W2   = (const float*)d_in[4];
    const float* b2   = (const float*)d_in[5];
    float* out = (float*)d_out;
    unsigned short* w1f = (unsigned short*)d_ws;   // 256*256 bf16 = 128KB, fragment-ordered

    prep_w1f<<<256, 256, 0, stream>>>(W1, w1f);

    const int nblocks = N_EDGES_C / 64;            // 9375, exact
    edge_mlp<<<nblocks, 512, 0, stream>>>(emd, eidx, w1f, b1, W2, b2, out);
}